// Round 7
// baseline (182.017 us; speedup 1.0000x reference)
//
#include <hip/hip_runtime.h>
#include <hip/hip_bf16.h>
#include <math.h>
#include <stdint.h>

#define NTOK 21824

typedef __attribute__((ext_vector_type(8)))  short bf16x8;
typedef __attribute__((ext_vector_type(4)))  float f32x4;
typedef __attribute__((ext_vector_type(16))) float f32x16;

__device__ __forceinline__ uint32_t f2bf(float f) {
    uint32_t u = __builtin_bit_cast(uint32_t, f);
    return (u + 0x7FFFu + ((u >> 16) & 1u)) >> 16;   // RNE
}
__device__ __forceinline__ uint32_t pkbf2(float lo, float hi) {
    __hip_bfloat162 h = __float22bfloat162_rn(float2{lo, hi});
    uint32_t r; __builtin_memcpy(&r, &h, 4);         // v_cvt_pk_bf16_f32
    return r;
}

// ws layout (uint16): cls_Wh @0, box_Wh @65536, cls_Wo @131072, box_Wo(pad 16x256) @151552
#define WOFF_CWH 0
#define WOFF_BWH 65536
#define WOFF_CWO 131072
#define WOFF_BWO 151552

__global__ void prep_weights(const float* __restrict__ cWh, const float* __restrict__ cWo,
                             const float* __restrict__ bWh, const float* __restrict__ bWo,
                             uint16_t* __restrict__ ws) {
    int i = blockIdx.x * 256 + threadIdx.x;
    if (i >= 155648) return;
    uint32_t v;
    if (i < 65536)       v = f2bf(cWh[i]);
    else if (i < 131072) v = f2bf(bWh[i - 65536]);
    else if (i < 151552) v = f2bf(cWo[i - 131072]);
    else { int j = i - 151552; v = (j < 1024) ? f2bf(bWo[j]) : 0u; }
    ws[i] = (uint16_t)v;
}

__global__ __launch_bounds__(512, 4) void dfd_fused(
    const float* __restrict__ fm0, const float* __restrict__ fm1,
    const float* __restrict__ fm2, const float* __restrict__ fm3,
    const float* __restrict__ fm4,
    const float* __restrict__ cls_bh, const float* __restrict__ cls_bo,
    const float* __restrict__ box_bh, const float* __restrict__ box_bo,
    const uint16_t* __restrict__ wbf,
    float* __restrict__ out)
{
    // 64 KB overlay: Xs[64 t][256 f] (phase 1-2) then Hs[64 t][512 hh] (phase 3-4)
    __shared__ uint16_t LB[64 * 512];
    uint16_t* Xs = LB;
    uint16_t* Hs = LB;

    const int tid  = threadIdx.x;
    const int lane = tid & 63;
    const int w    = tid >> 6;          // wave 0..7
    const int r    = lane & 15;
    const int q    = lane >> 4;
    const int col  = lane & 31;
    const int hi   = lane >> 5;
    const int n0   = blockIdx.x * 64;
    const int b    = blockIdx.y;

    const float* fm; int off, ls;
    if      (n0 < 16384) { fm = fm0; off = 0;     ls = 7; }
    else if (n0 < 20480) { fm = fm1; off = 16384; ls = 6; }
    else if (n0 < 21504) { fm = fm2; off = 20480; ls = 5; }
    else if (n0 < 21760) { fm = fm3; off = 21504; ls = 4; }
    else                 { fm = fm4; off = 21760; ls = 3; }
    const int dim = 1 << ls;
    const int hw  = dim * dim;
    const int p0  = n0 - off;

    // ---- stage: fm[b][f][p0+t] -> Xs[t][f^sw] bf16, packed b64 writes
    {
        const int t  = lane;
        const int sw = (t & 7) << 3;
        const float* src = fm + (size_t)b * 256 * hw + p0 + t;
        #pragma unroll
        for (int i = 0; i < 8; ++i) {
            const int f = w * 4 + i * 32;
            const float x0 = src[(size_t)(f + 0) * hw];
            const float x1 = src[(size_t)(f + 1) * hw];
            const float x2 = src[(size_t)(f + 2) * hw];
            const float x3 = src[(size_t)(f + 3) * hw];
            uint2 pk; pk.x = pkbf2(x0, x1); pk.y = pkbf2(x2, x3);
            *reinterpret_cast<uint2*>(&Xs[t * 256 + (f ^ sw)]) = pk;
        }
    }
    __syncthreads();

    // ---- G1 (32x32x16): C[h][t]. Wave w owns hh in [w*64, w*64+64) of the
    //      unified space (hh<256 = cls hidden, hh>=256 = box hidden).
    f32x16 acc[2][2];   // [mt = hh 32-tile][nt = token 32-tile]
    {
        #pragma unroll
        for (int mt = 0; mt < 2; ++mt)
            #pragma unroll
            for (int nt = 0; nt < 2; ++nt)
                #pragma unroll
                for (int e = 0; e < 16; ++e) acc[mt][nt][e] = 0.f;

        const int hh0 = w * 64;
        const uint16_t* Wbase = (w < 4) ? wbf + WOFF_CWH + hh0 * 256
                                        : wbf + WOFF_BWH + (hh0 - 256) * 256;
        const int kh = hi * 8;
        const uint16_t* Wr = Wbase + col * 256 + kh;   // A row = hh0 + mt*32 + col
        const int sw0 = (col & 7) << 3;                // (32+col)&7 == col&7

        #pragma unroll
        for (int ks = 0; ks < 16; ++ks) {
            const bf16x8 a0 = *(const bf16x8*)(Wr + ks * 16);
            const bf16x8 a1 = *(const bf16x8*)(Wr + 8192 + ks * 16);
            const int kx = (ks * 16 + kh) ^ sw0;
            const bf16x8 x0 = *(const bf16x8*)&Xs[col * 256 + kx];
            const bf16x8 x1 = *(const bf16x8*)&Xs[(32 + col) * 256 + kx];
            acc[0][0] = __builtin_amdgcn_mfma_f32_32x32x16_bf16(a0, x0, acc[0][0], 0, 0, 0);
            acc[0][1] = __builtin_amdgcn_mfma_f32_32x32x16_bf16(a0, x1, acc[0][1], 0, 0, 0);
            acc[1][0] = __builtin_amdgcn_mfma_f32_32x32x16_bf16(a1, x0, acc[1][0], 0, 0, 0);
            acc[1][1] = __builtin_amdgcn_mfma_f32_32x32x16_bf16(a1, x1, acc[1][1], 0, 0, 0);
        }
    }
    __syncthreads();   // all Xs reads done before Hs overwrites

    // ---- epilogue: bias+ReLU, pack 4 consecutive hh per b64 write
    {
        const int hh0 = w * 64;
        const float* bh_ = (w < 4) ? cls_bh + hh0 : box_bh + (hh0 - 256);
        #pragma unroll
        for (int mt = 0; mt < 2; ++mt) {
            #pragma unroll
            for (int nt = 0; nt < 2; ++nt) {
                const int t   = nt * 32 + col;
                const int swt = (t & 7) << 3;
                #pragma unroll
                for (int g = 0; g < 4; ++g) {
                    const int hb = mt * 32 + 8 * g + 4 * hi;   // C row = hb + (reg&3)
                    const f32x4 bv = *(const f32x4*)(bh_ + hb);
                    const float v0 = fmaxf(acc[mt][nt][4 * g + 0] + bv[0], 0.f);
                    const float v1 = fmaxf(acc[mt][nt][4 * g + 1] + bv[1], 0.f);
                    const float v2 = fmaxf(acc[mt][nt][4 * g + 2] + bv[2], 0.f);
                    const float v3 = fmaxf(acc[mt][nt][4 * g + 3] + bv[3], 0.f);
                    uint2 pk; pk.x = pkbf2(v0, v1); pk.y = pkbf2(v2, v3);
                    *reinterpret_cast<uint2*>(&Hs[t * 512 + ((hh0 + hb) ^ swt)]) = pk;
                }
            }
        }
    }
    __syncthreads();

    // ---- G2 (16x16x32): C[out][t]. wave = (token-tile nt2 = w&3, m-half = w>>2).
    //      m-half 0: cls tiles 0,1,2. m-half 1: cls tiles 3,4 + box.
    {
        const int nt2 = w & 3;
        const int mh  = w >> 2;
        const int t   = nt2 * 16 + r;
        const int swt = (t & 7) << 3;
        const uint16_t* hrow = &Hs[t * 512];

        f32x4 c[3];
        c[0] = {0.f,0.f,0.f,0.f}; c[1] = {0.f,0.f,0.f,0.f}; c[2] = {0.f,0.f,0.f,0.f};
        const int m0 = mh * 3;   // first cls tile index
        const uint16_t* WoA = wbf + WOFF_CWO + r * 256 + q * 8;
        const uint16_t* WoB = wbf + WOFF_BWO + r * 256 + q * 8;

        #pragma unroll
        for (int kq = 0; kq < 8; ++kq) {
            const bf16x8 hb = *(const bf16x8*)&hrow[(kq * 32 + q * 8) ^ swt];
            const bf16x8 aA = *(const bf16x8*)(WoA + (m0 + 0) * 4096 + kq * 32);
            const bf16x8 aB = *(const bf16x8*)(WoA + (m0 + 1) * 4096 + kq * 32);
            c[0] = __builtin_amdgcn_mfma_f32_16x16x32_bf16(aA, hb, c[0], 0, 0, 0);
            c[1] = __builtin_amdgcn_mfma_f32_16x16x32_bf16(aB, hb, c[1], 0, 0, 0);
            if (mh == 0) {
                const bf16x8 aC = *(const bf16x8*)(WoA + 2 * 4096 + kq * 32);
                c[2] = __builtin_amdgcn_mfma_f32_16x16x32_bf16(aC, hb, c[2], 0, 0, 0);
            } else {
                const bf16x8 hbb = *(const bf16x8*)&hrow[(256 + kq * 32 + q * 8) ^ swt];
                const bf16x8 aC  = *(const bf16x8*)(WoB + kq * 32);
                c[2] = __builtin_amdgcn_mfma_f32_16x16x32_bf16(aC, hbb, c[2], 0, 0, 0);
            }
        }

        // cls stores: lane holds out-cols m*16 + q*4 + (0..3) for token t -> float4
        float* orow = out + ((size_t)b * NTOK + n0 + t) * 84;
        const int ncls = (mh == 0) ? 3 : 2;
        #pragma unroll
        for (int i = 0; i < 3; ++i) {
            if (i < ncls) {
                const int m = m0 + i;
                const f32x4 bo = *(const f32x4*)(cls_bo + m * 16 + q * 4);
                f32x4 v;
                #pragma unroll
                for (int jj = 0; jj < 4; ++jj) v[jj] = c[i][jj] + bo[jj];
                *(f32x4*)(orow + m * 16 + q * 4) = v;
            }
        }
        // box decode: C rows 0..3 live in q==0 lanes (Wo pad rows 4..15 are zero)
        if (mh == 1 && q == 0) {
            const f32x4 bo = *(const f32x4*)box_bo;
            const float inv = 1.0f / (float)dim;
            const int p = p0 + t;
            const float d0 = tanhf(c[2][0] + bo[0]);
            const float d1 = tanhf(c[2][1] + bo[1]);
            const float d2 = tanhf(c[2][2] + bo[2]);
            const float d3 = tanhf(c[2][3] + bo[3]);
            f32x4 v;
            v[0] = ((float)(p & (dim - 1)) + 0.5f) * inv + 0.1f * d0;
            v[1] = ((float)(p >> ls) + 0.5f) * inv + 0.1f * d1;
            v[2] = exp2f(d2) * inv;
            v[3] = exp2f(d3) * inv;
            *(f32x4*)(orow + 80) = v;
        }
    }
}

extern "C" void kernel_launch(void* const* d_in, const int* in_sizes, int n_in,
                              void* d_out, int out_size, void* d_ws, size_t ws_size,
                              hipStream_t stream) {
    uint16_t* ws = (uint16_t*)d_ws;
    prep_weights<<<608, 256, 0, stream>>>(
        (const float*)d_in[5],  (const float*)d_in[7],
        (const float*)d_in[9],  (const float*)d_in[11], ws);
    dim3 grid(NTOK / 64, 8);   // 341 x 8 blocks, 512 threads
    dfd_fused<<<grid, 512, 0, stream>>>(
        (const float*)d_in[0], (const float*)d_in[1], (const float*)d_in[2],
        (const float*)d_in[3], (const float*)d_in[4],
        (const float*)d_in[6],  (const float*)d_in[8],
        (const float*)d_in[10], (const float*)d_in[12],
        ws, (float*)d_out);
}